// Round 2
// baseline (1042.239 us; speedup 1.0000x reference)
//
#include <hip/hip_runtime.h>

// Bottleneck_refine: B=16, C=1024, H=W=56, G=4, MS=7 (8x8 patches), MID=256.
// fp32 I/O (reference is jnp.float32). One workgroup per (b, pr, pc, g):
// 16*7*7*4 = 3136 blocks.
//
// Active block:  conv1 (1x1, 64x256@256x64) -> relu
//                conv2 (3x3 per-patch-pad, 9 tap-GEMMs 64x64@64x64) -> relu
//                conv3 (1x1, 256x64@64x64) -> +x residual -> relu
// Masked block:  out = relu(x) streaming.
// Activations held in LDS as bf16 (precision: 2% threshold), weights fp32.

typedef __attribute__((ext_vector_type(4))) unsigned short us4;

__device__ __forceinline__ float bf2f(unsigned short u) {
    union { unsigned int i; float f; } v; v.i = ((unsigned int)u) << 16; return v.f;
}
__device__ __forceinline__ unsigned short f2bf(float f) {
    union { float f; unsigned int i; } v; v.f = f;
    unsigned int u = v.i;
    return (unsigned short)((u + 0x7FFFu + ((u >> 16) & 1u)) >> 16);
}

__global__ __launch_bounds__(256, 2)
void bottleneck_kernel(const float* __restrict__ x,
                       const float* __restrict__ mask,
                       const float* __restrict__ w1,
                       const float* __restrict__ w2,
                       const float* __restrict__ w3,
                       float* __restrict__ out) {
    __shared__ unsigned short Xs[256 * 64];   // 32 KB  input slab (bf16) [ch][py*8+px]
    __shared__ unsigned short Y1s[64 * 100];  // 12.5 KB conv1 out (bf16), zero-padded 10x10
    __shared__ unsigned short Y2s[64 * 64];   // 8 KB   conv2 out (bf16)
    __shared__ float Wsf[64 * 64];            // 16 KB  weight staging fp32 [k][oc]

    const int tid = threadIdx.x;
    int bid = blockIdx.x;
    const int g = bid & 3;
    int p = bid >> 2;
    const int pc = p % 7; p /= 7;
    const int pr = p % 7;
    const int b  = p / 7;

    const float mval = mask[((b * 4 + g) * 7 + pr) * 7 + pc];
    const size_t xbase = (size_t)(b * 1024 + g * 256) * 3136
                       + (size_t)(pr * 8) * 56 + (size_t)(pc * 8);

    if (mval <= 0.f) {
        // streaming passthrough: out = relu(x) on this 256ch x 8x8 slab
        for (int k = 0; k < 8; k++) {
            int v = tid + k * 256;
            int ch = v >> 3, py = v & 7;
            size_t off = xbase + (size_t)ch * 3136 + (size_t)py * 56;
            float4 d0 = *(const float4*)(x + off);
            float4 d1 = *(const float4*)(x + off + 4);
            d0.x = fmaxf(d0.x, 0.f); d0.y = fmaxf(d0.y, 0.f);
            d0.z = fmaxf(d0.z, 0.f); d0.w = fmaxf(d0.w, 0.f);
            d1.x = fmaxf(d1.x, 0.f); d1.y = fmaxf(d1.y, 0.f);
            d1.z = fmaxf(d1.z, 0.f); d1.w = fmaxf(d1.w, 0.f);
            *(float4*)(out + off)     = d0;
            *(float4*)(out + off + 4) = d1;
        }
        return;
    }

    // ---- stage X slab into LDS as bf16 ----
    for (int k = 0; k < 8; k++) {
        int v = tid + k * 256;
        int ch = v >> 3, py = v & 7;
        const float* src = x + xbase + (size_t)ch * 3136 + (size_t)py * 56;
        float4 d0 = *(const float4*)src;
        float4 d1 = *(const float4*)(src + 4);
        us4 h0, h1;
        h0.x = f2bf(d0.x); h0.y = f2bf(d0.y); h0.z = f2bf(d0.z); h0.w = f2bf(d0.w);
        h1.x = f2bf(d1.x); h1.y = f2bf(d1.y); h1.z = f2bf(d1.z); h1.w = f2bf(d1.w);
        *(us4*)&Xs[ch * 64 + py * 8]     = h0;
        *(us4*)&Xs[ch * 64 + py * 8 + 4] = h1;
    }
    for (int i = tid; i < 6400; i += 256) Y1s[i] = 0;  // zero incl. pad border

    const int px0 = (tid & 15) * 4;  // 4 consecutive pixels (same row)
    const int oc0 = (tid >> 4) * 4;  // 4 output channels
    const int py  = px0 >> 3;
    const int pxl = px0 & 7;

    // ---- conv1: 64x256 @ 256x64, K tiled by 64 ----
    float a1[4][4];
#pragma unroll
    for (int i = 0; i < 4; i++)
#pragma unroll
        for (int j = 0; j < 4; j++) a1[i][j] = 0.f;

    for (int kc = 0; kc < 4; kc++) {
        __syncthreads();  // Wsf free to overwrite; covers Xs/Y1s init on kc=0
        {
            int oc = tid & 63, ic0 = (tid >> 6) * 16;
            const float* ws = w1 + (size_t)(g * 64 + oc) * 256 + kc * 64 + ic0;
            float tmp[16];
            *(float4*)(tmp)      = *(const float4*)(ws);
            *(float4*)(tmp + 4)  = *(const float4*)(ws + 4);
            *(float4*)(tmp + 8)  = *(const float4*)(ws + 8);
            *(float4*)(tmp + 12) = *(const float4*)(ws + 12);
#pragma unroll
            for (int j = 0; j < 16; j++) Wsf[(ic0 + j) * 64 + oc] = tmp[j];
        }
        __syncthreads();
#pragma unroll 4
        for (int ic = 0; ic < 64; ic++) {
            us4 xu = *(const us4*)&Xs[(kc * 64 + ic) * 64 + px0];
            float4 wf = *(const float4*)&Wsf[ic * 64 + oc0];
            float xf[4] = {bf2f(xu.x), bf2f(xu.y), bf2f(xu.z), bf2f(xu.w)};
            float wv[4] = {wf.x, wf.y, wf.z, wf.w};
#pragma unroll
            for (int i = 0; i < 4; i++)
#pragma unroll
                for (int j = 0; j < 4; j++) a1[i][j] += wv[i] * xf[j];
        }
    }
    // relu -> padded Y1 (bf16)
#pragma unroll
    for (int i = 0; i < 4; i++)
#pragma unroll
        for (int j = 0; j < 4; j++) {
            float v = a1[i][j] > 0.f ? a1[i][j] : 0.f;
            Y1s[(oc0 + i) * 100 + (py + 1) * 10 + (pxl + 1) + j] = f2bf(v);
        }

    // ---- conv2: 3x3 as 9 tap-GEMMs on padded Y1 ----
    float a2[4][4];
#pragma unroll
    for (int i = 0; i < 4; i++)
#pragma unroll
        for (int j = 0; j < 4; j++) a2[i][j] = 0.f;

    for (int tap = 0; tap < 9; tap++) {
        __syncthreads();  // Y1 writes visible (tap 0); Wsf free (taps 1..8)
        {
            int oc = tid & 63, ic0 = (tid >> 6) * 16;
            const float* ws = w2 + ((size_t)(g * 64 + oc) * 64 + ic0) * 9 + tap;
#pragma unroll
            for (int j = 0; j < 16; j++) Wsf[(ic0 + j) * 64 + oc] = ws[(size_t)j * 9];
        }
        __syncthreads();
        const int dy = tap / 3, dx = tap % 3;
        const int rbase = (py + dy) * 10 + (pxl + dx);
#pragma unroll 4
        for (int ic = 0; ic < 64; ic++) {
            const unsigned short* yrow = &Y1s[ic * 100 + rbase];
            float xf[4] = {bf2f(yrow[0]), bf2f(yrow[1]), bf2f(yrow[2]), bf2f(yrow[3])};
            float4 wf = *(const float4*)&Wsf[ic * 64 + oc0];
            float wv[4] = {wf.x, wf.y, wf.z, wf.w};
#pragma unroll
            for (int i = 0; i < 4; i++)
#pragma unroll
                for (int j = 0; j < 4; j++) a2[i][j] += wv[i] * xf[j];
        }
    }
    // relu -> Y2 (bf16)
#pragma unroll
    for (int i = 0; i < 4; i++) {
        us4 ov;
        ov.x = f2bf(a2[i][0] > 0.f ? a2[i][0] : 0.f);
        ov.y = f2bf(a2[i][1] > 0.f ? a2[i][1] : 0.f);
        ov.z = f2bf(a2[i][2] > 0.f ? a2[i][2] : 0.f);
        ov.w = f2bf(a2[i][3] > 0.f ? a2[i][3] : 0.f);
        *(us4*)&Y2s[(oc0 + i) * 64 + px0] = ov;
    }

    // ---- conv3: 256x64 @ 64x64 in 4 oc-chunks, fused residual+relu+store ----
    for (int cc = 0; cc < 4; cc++) {
        __syncthreads();  // Y2 writes visible (cc 0); Wsf free
        {
            int oc = tid & 63, ic0 = (tid >> 6) * 16;
            const float* ws = w3 + (size_t)(g * 256 + cc * 64 + oc) * 64 + ic0;
            float tmp[16];
            *(float4*)(tmp)      = *(const float4*)(ws);
            *(float4*)(tmp + 4)  = *(const float4*)(ws + 4);
            *(float4*)(tmp + 8)  = *(const float4*)(ws + 8);
            *(float4*)(tmp + 12) = *(const float4*)(ws + 12);
#pragma unroll
            for (int j = 0; j < 16; j++) Wsf[(ic0 + j) * 64 + oc] = tmp[j];
        }
        __syncthreads();
        float a3[4][4];
#pragma unroll
        for (int i = 0; i < 4; i++)
#pragma unroll
            for (int j = 0; j < 4; j++) a3[i][j] = 0.f;
#pragma unroll 4
        for (int ic = 0; ic < 64; ic++) {
            us4 xu = *(const us4*)&Y2s[ic * 64 + px0];
            float4 wf = *(const float4*)&Wsf[ic * 64 + oc0];
            float xf[4] = {bf2f(xu.x), bf2f(xu.y), bf2f(xu.z), bf2f(xu.w)};
            float wv[4] = {wf.x, wf.y, wf.z, wf.w};
#pragma unroll
            for (int i = 0; i < 4; i++)
#pragma unroll
                for (int j = 0; j < 4; j++) a3[i][j] += wv[i] * xf[j];
        }
#pragma unroll
        for (int i = 0; i < 4; i++) {
            int c = cc * 64 + oc0 + i;
            size_t off = xbase + (size_t)c * 3136 + (size_t)py * 56 + pxl;
            us4 xu = *(const us4*)&Xs[c * 64 + px0];
            float4 ov;
            ov.x = fmaxf(a3[i][0] + bf2f(xu.x), 0.f);
            ov.y = fmaxf(a3[i][1] + bf2f(xu.y), 0.f);
            ov.z = fmaxf(a3[i][2] + bf2f(xu.z), 0.f);
            ov.w = fmaxf(a3[i][3] + bf2f(xu.w), 0.f);
            *(float4*)(out + off) = ov;
        }
    }
}

extern "C" void kernel_launch(void* const* d_in, const int* in_sizes, int n_in,
                              void* d_out, int out_size, void* d_ws, size_t ws_size,
                              hipStream_t stream) {
    const float* x    = (const float*)d_in[0];
    const float* mask = (const float*)d_in[1];
    const float* w1   = (const float*)d_in[2];
    const float* w2   = (const float*)d_in[3];
    const float* w3   = (const float*)d_in[4];
    float* out = (float*)d_out;

    bottleneck_kernel<<<dim3(16 * 7 * 7 * 4), dim3(256), 0, stream>>>(
        x, mask, w1, w2, w3, out);
}

// Round 3
// 487.540 us; speedup vs baseline: 2.1378x; 2.1378x over previous
//
#include <hip/hip_runtime.h>

// Bottleneck_refine: B=16, C=1024, H=W=56, G=4, MS=7 (8x8 patches), MID=256.
// fp32 I/O. One workgroup (256 thr = 4 waves) per (b,pr,pc,g): 3136 blocks.
// MFMA rewrite: conv1/conv2/conv3 as 16x16x32 bf16 MFMA GEMMs.
//   conv1: C[64px x 64oc]  = XT[64x256] * W1^T, K=256 (2 K-halves staged)
//   conv2: 9 taps of C[64px x 64oc] += Y1p * W2tap^T, K=64 (double-buffered)
//   conv3: C[64px x 256oc] = Y2 * W3^T, K=64 (2 oc-halves staged)
// Residual read back from XT (bf16) in LDS; masked blocks stream relu(x).
//
// LDS overlay (70656 B -> 2 blocks/CU):
//   XT  [64][264]  live whole kernel (conv1 A + residual)
//   R2  = W1half[64][136] -> Y1p[100][72] -> W3half[128][72]  (sequential)
//   R3  = W2[2][64][72] double buffer -> Y2[64][72] (after conv2)

typedef __attribute__((ext_vector_type(8))) short bfrag;      // 8 bf16 (4 VGPR)
typedef __attribute__((ext_vector_type(8))) unsigned short us8;
typedef __attribute__((ext_vector_type(4))) float f4;

__device__ __forceinline__ float bf2f(unsigned short u) {
    union { unsigned int i; float f; } v; v.i = ((unsigned int)u) << 16; return v.f;
}
__device__ __forceinline__ unsigned short f2bf(float f) {
    union { float f; unsigned int i; } v; v.f = f;
    unsigned int u = v.i;
    return (unsigned short)((u + 0x7FFFu + ((u >> 16) & 1u)) >> 16);
}

#define XT_S 264   // XT stride (elems)
#define W1_S 136   // W1 half stride
#define S72  72    // Y1p / W2 / Y2 / W3 stride
#define R2_OFF 16896
#define R3_OFF 26112

__global__ __launch_bounds__(256, 2)
void bottleneck_kernel(const float* __restrict__ x,
                       const float* __restrict__ mask,
                       const float* __restrict__ w1,
                       const float* __restrict__ w2,
                       const float* __restrict__ w3,
                       float* __restrict__ out) {
    __shared__ __align__(16) unsigned short lds[35328];
    unsigned short* XT  = lds;             // [64][264]
    unsigned short* R2  = lds + R2_OFF;    // 9216 elems
    unsigned short* W2s = lds + R3_OFF;    // [2][64][72]
    unsigned short* Y2s = lds + R3_OFF;    // overlays W2 buf0 after conv2

    const int tid = threadIdx.x;
    int bid = blockIdx.x;
    const int g = bid & 3;
    int p = bid >> 2;
    const int pc = p % 7; p /= 7;
    const int pr = p % 7;
    const int b  = p / 7;

    const float mval = mask[((b * 4 + g) * 7 + pr) * 7 + pc];
    const size_t xbase = (size_t)(b * 1024 + g * 256) * 3136
                       + (size_t)(pr * 8) * 56 + (size_t)(pc * 8);

    if (mval <= 0.f) {  // streaming passthrough: out = relu(x)
        for (int k = 0; k < 8; k++) {
            int v = tid + k * 256;
            int ch = v >> 3, py = v & 7;
            size_t off = xbase + (size_t)ch * 3136 + (size_t)py * 56;
            float4 d0 = *(const float4*)(x + off);
            float4 d1 = *(const float4*)(x + off + 4);
            d0.x = fmaxf(d0.x, 0.f); d0.y = fmaxf(d0.y, 0.f);
            d0.z = fmaxf(d0.z, 0.f); d0.w = fmaxf(d0.w, 0.f);
            d1.x = fmaxf(d1.x, 0.f); d1.y = fmaxf(d1.y, 0.f);
            d1.z = fmaxf(d1.z, 0.f); d1.w = fmaxf(d1.w, 0.f);
            *(float4*)(out + off)     = d0;
            *(float4*)(out + off + 4) = d1;
        }
        return;
    }

    const int lane = tid & 63;
    const int wv   = tid >> 6;
    const int l15  = lane & 15;
    const int quad = lane >> 4;
    const int mrow = wv * 16 + l15;        // A-operand row (px) for this lane
    const int crow = wv * 16 + quad * 4;   // C/D row base (px) for this lane
    const int cpy  = crow >> 3, cpx0 = crow & 7;  // crow%8 is 0 or 4: same py for r=0..3

    // ---- stage X: fp32 [ch][8x8] -> bf16 XT[px][ic], packed pair writes ----
    for (int k = 0; k < 4; k++) {
        int v = tid + k * 256;             // 0..1023
        int py = v & 7, chp = v >> 3;      // chp 0..127
        int ch = chp * 2;
        const float* s0 = x + xbase + (size_t)ch * 3136 + (size_t)py * 56;
        const float* s1 = s0 + 3136;
        float4 a0 = *(const float4*)s0, a1 = *(const float4*)(s0 + 4);
        float4 b0 = *(const float4*)s1, b1 = *(const float4*)(s1 + 4);
        float af[8] = {a0.x,a0.y,a0.z,a0.w,a1.x,a1.y,a1.z,a1.w};
        float bg[8] = {b0.x,b0.y,b0.z,b0.w,b1.x,b1.y,b1.z,b1.w};
        int row0 = py * 8;
#pragma unroll
        for (int px = 0; px < 8; px++) {
            unsigned int u = (unsigned int)f2bf(af[px])
                           | ((unsigned int)f2bf(bg[px]) << 16);
            *(unsigned int*)&XT[(row0 + px) * XT_S + ch] = u;
        }
    }
    // ---- stage W1 half 0: [64oc][128ic] ----
    {
        int oc = tid & 63, ic0 = (tid >> 6) * 32;
        const float* ws = w1 + (size_t)(g * 64 + oc) * 256 + ic0;
#pragma unroll
        for (int j = 0; j < 4; j++) {
            float4 f0 = *(const float4*)(ws + j * 8);
            float4 f1 = *(const float4*)(ws + j * 8 + 4);
            us8 o;
            o[0]=f2bf(f0.x); o[1]=f2bf(f0.y); o[2]=f2bf(f0.z); o[3]=f2bf(f0.w);
            o[4]=f2bf(f1.x); o[5]=f2bf(f1.y); o[6]=f2bf(f1.z); o[7]=f2bf(f1.w);
            *(us8*)&R2[oc * W1_S + ic0 + j * 8] = o;
        }
    }
    __syncthreads();

    // ---- conv1: acc1[4 oc-tiles], K=256 in 2 halves of 128 ----
    f4 acc1[4];
#pragma unroll
    for (int nt = 0; nt < 4; nt++) acc1[nt] = (f4){0.f, 0.f, 0.f, 0.f};

    for (int h = 0; h < 2; h++) {
        if (h) {
            __syncthreads();   // all waves done with half 0 weights
            int oc = tid & 63, ic0 = (tid >> 6) * 32;
            const float* ws = w1 + (size_t)(g * 64 + oc) * 256 + 128 + ic0;
#pragma unroll
            for (int j = 0; j < 4; j++) {
                float4 f0 = *(const float4*)(ws + j * 8);
                float4 f1 = *(const float4*)(ws + j * 8 + 4);
                us8 o;
                o[0]=f2bf(f0.x); o[1]=f2bf(f0.y); o[2]=f2bf(f0.z); o[3]=f2bf(f0.w);
                o[4]=f2bf(f1.x); o[5]=f2bf(f1.y); o[6]=f2bf(f1.z); o[7]=f2bf(f1.w);
                *(us8*)&R2[oc * W1_S + ic0 + j * 8] = o;
            }
            __syncthreads();
        }
#pragma unroll
        for (int ks = 0; ks < 4; ks++) {
            bfrag a = *(const bfrag*)&XT[mrow * XT_S + h * 128 + ks * 32 + quad * 8];
#pragma unroll
            for (int nt = 0; nt < 4; nt++) {
                bfrag bb = *(const bfrag*)&R2[(nt * 16 + l15) * W1_S + ks * 32 + quad * 8];
                acc1[nt] = __builtin_amdgcn_mfma_f32_16x16x32_bf16(a, bb, acc1[nt], 0, 0, 0);
            }
        }
    }
    __syncthreads();  // W1 dead; R2 -> Y1p

    // ---- Y1p: zero 36 border rows, write relu(acc1) to interior ----
    for (int i = tid; i < 36 * 72; i += 256) {
        int j = i / 72, c = i - j * 72;
        int r = (j < 10) ? j : (j < 20 ? 80 + j
                                       : 10 + ((j - 20) >> 1) * 10 + ((j - 20) & 1) * 9);
        R2[r * S72 + c] = 0;
    }
#pragma unroll
    for (int nt = 0; nt < 4; nt++)
#pragma unroll
        for (int r = 0; r < 4; r++) {
            int px = crow + r;
            int rowp = ((px >> 3) + 1) * 10 + (px & 7) + 1;
            float v = acc1[nt][r]; v = v > 0.f ? v : 0.f;
            R2[rowp * S72 + nt * 16 + l15] = f2bf(v);
        }
    // stage W2 tap 0 into buf 0 (R3, independent region)
    {
        int oc = tid & 63, ic0 = (tid >> 6) * 16;
        const float* ws = w2 + ((size_t)(g * 64 + oc) * 64 + ic0) * 9;
        float t[16];
#pragma unroll
        for (int j = 0; j < 16; j++) t[j] = ws[(size_t)j * 9];
        us8 o0, o1;
#pragma unroll
        for (int j = 0; j < 8; j++) { o0[j] = f2bf(t[j]); o1[j] = f2bf(t[j + 8]); }
        *(us8*)&W2s[oc * S72 + ic0]     = o0;
        *(us8*)&W2s[oc * S72 + ic0 + 8] = o1;
    }
    __syncthreads();

    // ---- conv2: 9 taps, W2 double-buffered, 1 barrier per tap ----
    f4 acc2[4];
#pragma unroll
    for (int nt = 0; nt < 4; nt++) acc2[nt] = (f4){0.f, 0.f, 0.f, 0.f};
    const int apy = mrow >> 3, apx = mrow & 7;

    for (int tap = 0; tap < 9; tap++) {
        const int buf = (tap & 1) * 4608;
        // issue next tap's global loads first (latency overlap with MFMAs)
        float t[16];
        int oc = tid & 63, ic0 = (tid >> 6) * 16;
        if (tap < 8) {
            const float* ws = w2 + ((size_t)(g * 64 + oc) * 64 + ic0) * 9 + tap + 1;
#pragma unroll
            for (int j = 0; j < 16; j++) t[j] = ws[(size_t)j * 9];
        }
        const int rowp = (apy + tap / 3) * 10 + apx + tap % 3;
#pragma unroll
        for (int ks = 0; ks < 2; ks++) {
            bfrag a = *(const bfrag*)&R2[rowp * S72 + ks * 32 + quad * 8];
#pragma unroll
            for (int nt = 0; nt < 4; nt++) {
                bfrag bb = *(const bfrag*)&W2s[buf + (nt * 16 + l15) * S72 + ks * 32 + quad * 8];
                acc2[nt] = __builtin_amdgcn_mfma_f32_16x16x32_bf16(a, bb, acc2[nt], 0, 0, 0);
            }
        }
        if (tap < 8) {
            us8 o0, o1;
#pragma unroll
            for (int j = 0; j < 8; j++) { o0[j] = f2bf(t[j]); o1[j] = f2bf(t[j + 8]); }
            int nb = 4608 - buf;
            *(us8*)&W2s[nb + oc * S72 + ic0]     = o0;
            *(us8*)&W2s[nb + oc * S72 + ic0 + 8] = o1;
        }
        __syncthreads();
    }

    // ---- Y2 = relu(acc2) (overlays W2 buf0); stage W3 half 0 into R2 ----
#pragma unroll
    for (int nt = 0; nt < 4; nt++)
#pragma unroll
        for (int r = 0; r < 4; r++) {
            int px = crow + r;
            float v = acc2[nt][r]; v = v > 0.f ? v : 0.f;
            Y2s[px * S72 + nt * 16 + l15] = f2bf(v);
        }
    {
        int ocl = tid & 127, ic0 = (tid >> 7) * 32;
        const float* ws = w3 + (size_t)(g * 256 + ocl) * 64 + ic0;
#pragma unroll
        for (int j = 0; j < 4; j++) {
            float4 f0 = *(const float4*)(ws + j * 8);
            float4 f1 = *(const float4*)(ws + j * 8 + 4);
            us8 o;
            o[0]=f2bf(f0.x); o[1]=f2bf(f0.y); o[2]=f2bf(f0.z); o[3]=f2bf(f0.w);
            o[4]=f2bf(f1.x); o[5]=f2bf(f1.y); o[6]=f2bf(f1.z); o[7]=f2bf(f1.w);
            *(us8*)&R2[ocl * S72 + ic0 + j * 8] = o;
        }
    }
    __syncthreads();

    // ---- conv3: 2 halves of 128 oc; fused residual+relu+store ----
    for (int hh = 0; hh < 2; hh++) {
        if (hh) {
            __syncthreads();
            int ocl = tid & 127, ic0 = (tid >> 7) * 32;
            const float* ws = w3 + (size_t)(g * 256 + 128 + ocl) * 64 + ic0;
#pragma unroll
            for (int j = 0; j < 4; j++) {
                float4 f0 = *(const float4*)(ws + j * 8);
                float4 f1 = *(const float4*)(ws + j * 8 + 4);
                us8 o;
                o[0]=f2bf(f0.x); o[1]=f2bf(f0.y); o[2]=f2bf(f0.z); o[3]=f2bf(f0.w);
                o[4]=f2bf(f1.x); o[5]=f2bf(f1.y); o[6]=f2bf(f1.z); o[7]=f2bf(f1.w);
                *(us8*)&R2[ocl * S72 + ic0 + j * 8] = o;
            }
            __syncthreads();
        }
        f4 acc3[8];
#pragma unroll
        for (int nt = 0; nt < 8; nt++) acc3[nt] = (f4){0.f, 0.f, 0.f, 0.f};
#pragma unroll
        for (int ks = 0; ks < 2; ks++) {
            bfrag a = *(const bfrag*)&Y2s[mrow * S72 + ks * 32 + quad * 8];
#pragma unroll
            for (int nt = 0; nt < 8; nt++) {
                bfrag bb = *(const bfrag*)&R2[(nt * 16 + l15) * S72 + ks * 32 + quad * 8];
                acc3[nt] = __builtin_amdgcn_mfma_f32_16x16x32_bf16(a, bb, acc3[nt], 0, 0, 0);
            }
        }
        // epilogue: 4 consecutive px (same row) per lane -> float4 store
#pragma unroll
        for (int nt = 0; nt < 8; nt++) {
            int oc = hh * 128 + nt * 16 + l15;
            float4 ov;
            float r0 = acc3[nt][0] + bf2f(XT[(crow + 0) * XT_S + oc]);
            float r1 = acc3[nt][1] + bf2f(XT[(crow + 1) * XT_S + oc]);
            float r2 = acc3[nt][2] + bf2f(XT[(crow + 2) * XT_S + oc]);
            float r3 = acc3[nt][3] + bf2f(XT[(crow + 3) * XT_S + oc]);
            ov.x = fmaxf(r0, 0.f); ov.y = fmaxf(r1, 0.f);
            ov.z = fmaxf(r2, 0.f); ov.w = fmaxf(r3, 0.f);
            *(float4*)(out + xbase + (size_t)oc * 3136 + (size_t)cpy * 56 + cpx0) = ov;
        }
    }
}

extern "C" void kernel_launch(void* const* d_in, const int* in_sizes, int n_in,
                              void* d_out, int out_size, void* d_ws, size_t ws_size,
                              hipStream_t stream) {
    const float* x    = (const float*)d_in[0];
    const float* mask = (const float*)d_in[1];
    const float* w1   = (const float*)d_in[2];
    const float* w2   = (const float*)d_in[3];
    const float* w3   = (const float*)d_in[4];
    float* out = (float*)d_out;

    bottleneck_kernel<<<dim3(16 * 7 * 7 * 4), dim3(256), 0, stream>>>(
        x, mask, w1, w2, w3, out);
}